// Round 5
// baseline (342.200 us; speedup 1.0000x reference)
//
#include <hip/hip_runtime.h>
#include <hip/hip_bf16.h>

#define Bb 128
#define Nn 4096
#define Ff 32
#define Ee 16
#define Hh 7
#define EH 112
#define NROW (Bb*Nn)
#define NBLK 2048           // phi/enc blocks: 256 rows each

typedef __attribute__((ext_vector_type(8))) short  bf16x8;
typedef __attribute__((ext_vector_type(4))) float  f32x4;
typedef __attribute__((ext_vector_type(4))) unsigned int u32x4;
typedef __attribute__((ext_vector_type(2))) unsigned int u32x2;

__device__ inline unsigned pack2(float a, float b) {
    __hip_bfloat162 h = __float22bfloat162_rn(make_float2(a, b));
    return *reinterpret_cast<unsigned*>(&h);
}
union BF8 { unsigned u[4]; bf16x8 v; u32x4 q; };

// ---------------------------------------------------------------- encoder ---
__global__ __launch_bounds__(256) void enc_kernel(
    const float* __restrict__ X,
    const float* __restrict__ W1, const float* __restrict__ b1,
    const float* __restrict__ W2, const float* __restrict__ b2,
    const float* __restrict__ W3, const float* __restrict__ b3,
    const float* __restrict__ g,  const float* __restrict__ be,
    const float* __restrict__ Wagg0, const int* __restrict__ avail,
    unsigned short* __restrict__ XeBF, float* __restrict__ acc0)
{
    __shared__ float sW1[Ff*Ee], sW2[Ee*Ee], sW3[Ee*Ee];
    __shared__ float sb1[Ee], sb2[Ee], sb3[Ee], sg[Ee], sbe[Ee];
    __shared__ float sWq[Ee*Hh];
    __shared__ float red[256][8];
    int tid = threadIdx.x;
    for (int i = tid; i < Ff*Ee; i += 256) sW1[i] = W1[i];
    for (int i = tid; i < Ee*Ee; i += 256) { sW2[i] = W2[i]; sW3[i] = W3[i]; }
    if (tid < Ee) { sb1[tid]=b1[tid]; sb2[tid]=b2[tid]; sb3[tid]=b3[tid];
                    sg[tid]=g[tid];   sbe[tid]=be[tid]; }
    if (tid < Ee*Hh) sWq[tid] = Wagg0[tid];
    __syncthreads();

    size_t row = (size_t)blockIdx.x * 256u + (unsigned)tid;
    const float4* xr = reinterpret_cast<const float4*>(X + row * Ff);
    float x[Ff];
    #pragma unroll
    for (int i = 0; i < Ff/4; ++i) {
        float4 v = xr[i];
        x[4*i+0]=v.x; x[4*i+1]=v.y; x[4*i+2]=v.z; x[4*i+3]=v.w;
    }
    float h1[Ee];
    #pragma unroll
    for (int e = 0; e < Ee; ++e) h1[e] = sb1[e];
    #pragma unroll 4
    for (int k = 0; k < Ff; ++k) {
        float xk = x[k];
        #pragma unroll
        for (int e = 0; e < Ee; ++e) h1[e] = fmaf(xk, sW1[k*Ee+e], h1[e]);
    }
    #pragma unroll
    for (int e = 0; e < Ee; ++e) h1[e] = fmaxf(h1[e], 0.f);

    float h2[Ee];
    #pragma unroll
    for (int e = 0; e < Ee; ++e) h2[e] = sb2[e];
    #pragma unroll 4
    for (int k = 0; k < Ee; ++k) {
        float hk = h1[k];
        #pragma unroll
        for (int e = 0; e < Ee; ++e) h2[e] = fmaf(hk, sW2[k*Ee+e], h2[e]);
    }
    #pragma unroll
    for (int e = 0; e < Ee; ++e) h2[e] = fmaxf(h2[e], 0.f);

    float z[Ee];
    #pragma unroll
    for (int e = 0; e < Ee; ++e) z[e] = sb3[e];
    #pragma unroll 4
    for (int k = 0; k < Ee; ++k) {
        float hk = h2[k];
        #pragma unroll
        for (int e = 0; e < Ee; ++e) z[e] = fmaf(hk, sW3[k*Ee+e], z[e]);
    }
    float m = 0.f;
    #pragma unroll
    for (int e = 0; e < Ee; ++e) m += z[e];
    m *= (1.f/Ee);
    float v = 0.f;
    #pragma unroll
    for (int e = 0; e < Ee; ++e) { float d = z[e]-m; v += d*d; }
    v *= (1.f/Ee);
    float inv = rsqrtf(v + 1e-6f);
    #pragma unroll
    for (int e = 0; e < Ee; ++e) z[e] = (z[e]-m)*inv*sg[e] + sbe[e];

    unsigned us[8];
    #pragma unroll
    for (int j = 0; j < 8; ++j) us[j] = pack2(z[2*j], z[2*j+1]);
    u32x4 lo = {us[0],us[1],us[2],us[3]};
    u32x4 hi = {us[4],us[5],us[6],us[7]};
    u32x4* xo = reinterpret_cast<u32x4*>(XeBF + row*Ee);
    xo[0] = lo; xo[1] = hi;

    // zbar_0 partials
    float af = (float)avail[row];
    float fc[Hh];
    #pragma unroll
    for (int h = 0; h < Hh; ++h) fc[h] = 0.f;
    #pragma unroll
    for (int e = 0; e < Ee; ++e) {
        float z2 = z[e]*z[e];
        #pragma unroll
        for (int h = 0; h < Hh; ++h) fc[h] = fmaf(z2, sWq[e*Hh+h], fc[h]);
    }
    #pragma unroll
    for (int h = 0; h < Hh; ++h) red[tid][h] = af * fc[h];
    red[tid][7] = af;
    __syncthreads();
    for (int s = 128; s > 0; s >>= 1) {
        if (tid < s) {
            #pragma unroll
            for (int q2 = 0; q2 < 8; ++q2) red[tid][q2] += red[tid+s][q2];
        }
        __syncthreads();
    }
    if (tid < 8) atomicAdd(&acc0[(blockIdx.x >> 4)*8 + tid], red[0][tid]);
}

// -------------------------------------------------- weight fragment packer --
// Biases folded into the K-pad: W1F k=16 row = b1; W2F k=112 row = b2.
__global__ __launch_bounds__(256) void wpack(
    const float* __restrict__ W_phi2, const float* __restrict__ W_phi1,
    const float* __restrict__ b_phi1, const float* __restrict__ b_phi2,
    unsigned short* __restrict__ W2F, unsigned short* __restrict__ W1F)
{
    int idx = blockIdx.x*256 + threadIdx.x;
    if (idx < 3*28*64) {
        int d = idx / (28*64); int r = idx % (28*64);
        int f = r >> 6, l = r & 63;
        int lg = l >> 4, li = l & 15, mt = f >> 2, kt = f & 3;
        const float* W2g = W_phi2 + (size_t)d*EH*EH;
        const float* b2g = b_phi2 + (size_t)d*EH;
        int mm = mt*16 + li;
        unsigned v[4];
        #pragma unroll
        for (int jj = 0; jj < 4; ++jj) {
            int k0 = kt*32 + lg*8 + jj*2;
            float a = (k0 < EH) ? W2g[(size_t)k0*EH + mm]
                                : (k0 == EH ? b2g[mm] : 0.f);
            float c = (k0+1 < EH) ? W2g[(size_t)(k0+1)*EH + mm] : 0.f;
            v[jj] = pack2(a, c);
        }
        u32x4 q = {v[0], v[1], v[2], v[3]};
        *reinterpret_cast<u32x4*>(W2F + (size_t)idx*8) = q;
    } else if (idx < 3*28*64 + 3*7*64) {
        int r2 = idx - 3*28*64;
        int d = r2 / (7*64); int r = r2 % (7*64);
        int mt = r >> 6, l = r & 63;
        int g = l >> 4, i = l & 15;
        const float* W1g = W_phi1 + (size_t)d*Ee*EH;
        const float* b1g = b_phi1 + (size_t)d*EH;
        int mm = mt*16 + i;
        unsigned v[4];
        #pragma unroll
        for (int jj = 0; jj < 4; ++jj) {
            float a = 0.f, c = 0.f;
            if (g < 2) {
                a = W1g[(size_t)(g*8 + jj*2)  *EH + mm];
                c = W1g[(size_t)(g*8 + jj*2+1)*EH + mm];
            } else if (g == 2 && jj == 0) {
                a = b1g[mm];                    // k=16 bias row
            }
            v[jj] = pack2(a, c);
        }
        u32x4 q = {v[0], v[1], v[2], v[3]};
        *reinterpret_cast<u32x4*>(W1F + (size_t)r2*8) = q;
    }
}

// ------------------------------------- phi via MFMA + fused zbar (+proj) ----
// LDS: sP1 only (XOR-swizzled, PS=128). W1/W2 fragments stream from global
// (L1-resident: 28 KB). 4 blocks/CU target.
template<bool LAST>
__global__ __launch_bounds__(256, 4) void phi_mfma(
    const unsigned short* __restrict__ Zin,   // bf16 [NROW][16]
    const unsigned short* __restrict__ Xe,    // bf16 [NROW][16]
    unsigned short* __restrict__ Zout,
    const float* __restrict__ accIn, const float* __restrict__ baggD,
    const float* __restrict__ WaggN, float* __restrict__ accN,
    const int* __restrict__ avail,
    const unsigned short* __restrict__ W1F,   // packed A-frags [7][64][8]
    const unsigned short* __restrict__ W2F,   // packed A-frags [28][64][8]
    const float* __restrict__ gg,  const float* __restrict__ beg,
    const float* __restrict__ Wp,  const float* __restrict__ bp,
    float* __restrict__ out)
{
    __shared__ __align__(16) unsigned short sP1[4][2][16*128];  // 32 KB
    __shared__ __align__(16) float sGZ[EH];

    int tid  = threadIdx.x;
    int wave = tid >> 6, lane = tid & 63;
    int g = lane >> 4, i = lane & 15;
    int i7 = i & 7;

    // zero sP1 (cols 112..127 stay {1.0-col, zeros} forever)
    for (int p = tid; p < (4*2*16*128)/8; p += 256) {
        u32x4 zq = {0u,0u,0u,0u};
        reinterpret_cast<u32x4*>(&sP1[0][0][0])[p] = zq;
    }

    int b = blockIdx.x >> 4;                     // 16 blocks per batch
    float cntb = accIn[b*8 + 7];
    float cden = fmaxf(cntb, 1.f);
    float zb[Hh];
    #pragma unroll
    for (int h = 0; h < Hh; ++h)
        zb[h] = (accIn[b*8 + h] + baggD[h]*cntb) / cden * (1.f/Hh);
    if (tid < EH) sGZ[tid] = gg[tid] * zb[tid >> 4];
    __syncthreads();

    // ones column at col 112 (16B-block 14), both buffers of this wave
    if (g == 0) {
        int idx = i*128 + ((14 ^ i7) << 3);
        sP1[wave][0][idx] = 0x3F80;
        sP1[wave][1][idx] = 0x3F80;
    }

    float Gz[4] = {0,0,0,0}, Bz[4] = {0,0,0,0};
    #pragma unroll
    for (int mt = 0; mt < 7; ++mt) {
        f32x4 gv = *reinterpret_cast<const f32x4*>(&sGZ[mt*16 + 4*g]);
        f32x4 bv = *reinterpret_cast<const f32x4*>(beg + mt*16 + 4*g);
        #pragma unroll
        for (int r = 0; r < 4; ++r) { Gz[r] += gv[r]; Bz[r] += bv[r]*zb[mt]; }
    }
    float wpa[4] = {0,0,0,0}, wpb[4] = {0,0,0,0}, bp0 = 0.f, bp1 = 0.f;
    if (LAST) {
        f32x4 u0 = *reinterpret_cast<const f32x4*>(Wp + 8*g);
        f32x4 u1 = *reinterpret_cast<const f32x4*>(Wp + 8*g + 4);
        wpa[0]=u0[0]; wpa[1]=u0[2]; wpa[2]=u1[0]; wpa[3]=u1[2];
        wpb[0]=u0[1]; wpb[1]=u0[3]; wpb[2]=u1[1]; wpb[3]=u1[3];
        bp0 = bp[0]; bp1 = bp[1];
    }
    float wacc2[4] = {0,0,0,0};
    float wcnt = 0.f;

    size_t r0 = (size_t)(blockIdx.x*16 + wave*4) * 16;
    unsigned short* p1A = &sP1[wave][0][0];
    unsigned short* p1B = &sP1[wave][1][0];
    const f32x4 zz = {0.f,0.f,0.f,0.f};

    auto epi = [&](const f32x4 (&d2)[7], size_t row0, float af) {
        // moments (independent reduce chains)
        float s = 0.f, q = 0.f;
        #pragma unroll
        for (int mt = 0; mt < 7; ++mt) {
            #pragma unroll
            for (int r = 0; r < 4; ++r) { float v = d2[mt][r]; s += v; q = fmaf(v,v,q); }
        }
        s += __shfl_xor(s, 16); q += __shfl_xor(q, 16);
        s += __shfl_xor(s, 32); q += __shfl_xor(q, 32);
        float m = s * (1.f/EH);
        float var = fmaf(-m, m, q * (1.f/EH));
        float inv = rsqrtf(var + 1e-6f);

        float S1[4] = {0,0,0,0};
        #pragma unroll
        for (int mt = 0; mt < 7; ++mt) {
            f32x4 gv = *reinterpret_cast<const f32x4*>(&sGZ[mt*16 + 4*g]);
            #pragma unroll
            for (int r = 0; r < 4; ++r) S1[r] = fmaf(d2[mt][r], gv[r], S1[r]);
        }
        u32x2 zu = __builtin_nontemporal_load(
            reinterpret_cast<const u32x2*>(Zin + (row0 + i)*Ee + 4*g));
        unsigned lo = zu[0], hi = zu[1];
        float zv[4];
        zv[0] = __uint_as_float((lo & 0xFFFFu) << 16);
        zv[1] = __uint_as_float(lo & 0xFFFF0000u);
        zv[2] = __uint_as_float((hi & 0xFFFFu) << 16);
        zv[3] = __uint_as_float(hi & 0xFFFF0000u);
        float zn[4];
        #pragma unroll
        for (int r = 0; r < 4; ++r)
            zn[r] = zv[r] + fmaf(-m, Gz[r], S1[r]) * inv + Bz[r];

        if (!LAST) {
            u32x2 w = {pack2(zn[0], zn[1]), pack2(zn[2], zn[3])};
            *reinterpret_cast<u32x2*>(Zout + (row0 + i)*Ee + 4*g) = w;
            #pragma unroll
            for (int r = 0; r < 4; ++r) wacc2[r] = fmaf(af, zn[r]*zn[r], wacc2[r]);
            wcnt += af;
        } else {
            float o0 = zn[0]*wpa[0] + zn[1]*wpa[1] + zn[2]*wpa[2] + zn[3]*wpa[3];
            float o1 = zn[0]*wpb[0] + zn[1]*wpb[1] + zn[2]*wpb[2] + zn[3]*wpb[3];
            o0 += __shfl_xor(o0, 16); o0 += __shfl_xor(o0, 32);
            o1 += __shfl_xor(o1, 16); o1 += __shfl_xor(o1, 32);
            if (g == 0) {
                float2 o; o.x = o0 + bp0; o.y = o1 + bp1;
                *reinterpret_cast<float2*>(out + (row0 + i)*2) = o;
            }
        }
    };

    auto pair = [&](size_t rowA) {
        // B-frags (Xe rows; g=2 carries 1.0 at k=16 for the bias row)
        BF8 bz_; bz_.u[0]=bz_.u[1]=bz_.u[2]=bz_.u[3]=0u;
        if (g == 2) bz_.u[0] = 0x00003F80u;
        bf16x8 bxA = bz_.v, bxB = bz_.v;
        if (g < 2) {
            bxA = __builtin_nontemporal_load(
                reinterpret_cast<const bf16x8*>(Xe + (rowA + i)*Ee + g*8));
            bxB = __builtin_nontemporal_load(
                reinterpret_cast<const bf16x8*>(Xe + (rowA + 16 + i)*Ee + g*8));
        }
        float afA = 0.f, afB = 0.f;
        if (!LAST) {
            afA = (float)__builtin_nontemporal_load(avail + rowA + i);
            afB = (float)__builtin_nontemporal_load(avail + rowA + 16 + i);
        }
        // W1 A-frags from global (L1-hot)
        bf16x8 aW1[7];
        #pragma unroll
        for (int mt = 0; mt < 7; ++mt)
            aW1[mt] = *reinterpret_cast<const bf16x8*>(W1F + (size_t)(mt*64 + lane)*8);
        // phi1 both tiles, pack, swizzled LDS store
        #pragma unroll
        for (int mt = 0; mt < 7; ++mt) {
            f32x4 dA = __builtin_amdgcn_mfma_f32_16x16x32_bf16(aW1[mt], bxA, zz, 0,0,0);
            f32x4 dB = __builtin_amdgcn_mfma_f32_16x16x32_bf16(aW1[mt], bxB, zz, 0,0,0);
            #pragma unroll
            for (int r = 0; r < 4; ++r) { dA[r] = fmaxf(dA[r],0.f); dB[r] = fmaxf(dB[r],0.f); }
            u32x2 wA = {pack2(dA[0],dA[1]), pack2(dA[2],dA[3])};
            u32x2 wB = {pack2(dB[0],dB[1]), pack2(dB[2],dB[3])};
            int widx = i*128 + (((2*mt + (g>>1)) ^ i7) << 3) + ((g&1) << 2);
            *reinterpret_cast<u32x2*>(&p1A[widx]) = wA;
            *reinterpret_cast<u32x2*>(&p1B[widx]) = wB;
        }
        // phi2 both tiles; W2 A-frags from global (L1-hot), shared across pair
        f32x4 d2A[7], d2B[7];
        #pragma unroll
        for (int mt = 0; mt < 7; ++mt) { d2A[mt] = zz; d2B[mt] = zz; }
        #pragma unroll
        for (int kt = 0; kt < 4; ++kt) {
            int ridx = i*128 + (((4*kt + g) ^ i7) << 3);
            bf16x8 bpA = *reinterpret_cast<const bf16x8*>(&p1A[ridx]);
            bf16x8 bpB = *reinterpret_cast<const bf16x8*>(&p1B[ridx]);
            #pragma unroll
            for (int mt = 0; mt < 7; ++mt) {
                bf16x8 a = *reinterpret_cast<const bf16x8*>(
                    W2F + (size_t)((mt*4 + kt)*64 + lane)*8);
                d2A[mt] = __builtin_amdgcn_mfma_f32_16x16x32_bf16(a, bpA, d2A[mt], 0,0,0);
                d2B[mt] = __builtin_amdgcn_mfma_f32_16x16x32_bf16(a, bpB, d2B[mt], 0,0,0);
            }
        }
        epi(d2A, rowA, afA);
        epi(d2B, rowA + 16, afB);
    };

    pair(r0);
    pair(r0 + 32);

    if (!LAST) {
        // deferred zbar contraction + wave reduce
        float f[Hh];
        #pragma unroll
        for (int h = 0; h < Hh; ++h) {
            float a = 0.f;
            #pragma unroll
            for (int r = 0; r < 4; ++r)
                a = fmaf(WaggN[(4*g + r)*Hh + h], wacc2[r], a);
            f[h] = a;
        }
        #pragma unroll
        for (int off = 1; off < 64; off <<= 1) {
            #pragma unroll
            for (int h = 0; h < Hh; ++h) f[h] += __shfl_xor(f[h], off);
            wcnt += __shfl_xor(wcnt, off);
        }
        if (lane == 0) {
            #pragma unroll
            for (int h = 0; h < Hh; ++h) atomicAdd(&accN[b*8 + h], f[h]);
            atomicAdd(&accN[b*8 + 7], wcnt * 0.25f);
        }
    }
}

// ---------------------------------------------------------------- launcher --
extern "C" void kernel_launch(void* const* d_in, const int* in_sizes, int n_in,
                              void* d_out, int out_size, void* d_ws, size_t ws_size,
                              hipStream_t stream)
{
    const float* X      = (const float*)d_in[0];
    const int*   avail  = (const int*)  d_in[1];
    const float* W_enc1 = (const float*)d_in[2];  const float* b_enc1 = (const float*)d_in[3];
    const float* W_enc2 = (const float*)d_in[4];  const float* b_enc2 = (const float*)d_in[5];
    const float* W_enc3 = (const float*)d_in[6];  const float* b_enc3 = (const float*)d_in[7];
    const float* g_enc  = (const float*)d_in[8];  const float* be_enc = (const float*)d_in[9];
    const float* W_agg  = (const float*)d_in[10]; const float* b_agg  = (const float*)d_in[11];
    const float* W_phi1 = (const float*)d_in[12]; const float* b_phi1 = (const float*)d_in[13];
    const float* W_phi2 = (const float*)d_in[14]; const float* b_phi2 = (const float*)d_in[15];
    const float* g_phi  = (const float*)d_in[16]; const float* be_phi = (const float*)d_in[17];
    const float* W_proj = (const float*)d_in[18]; const float* b_proj = (const float*)d_in[19];
    float* out = (float*)d_out;

    char* ws = (char*)d_ws;
    unsigned short* XeBF = (unsigned short*)ws;                        // 16 MiB
    unsigned short* Zb   = (unsigned short*)(ws + (size_t)NROW*Ee*2);  // 16 MiB
    char* p = ws + 2*(size_t)NROW*Ee*2;
    float* acc = (float*)p;                  p += 3*Bb*8*sizeof(float);
    unsigned short* W2F = (unsigned short*)p; p += (size_t)3*28*512*2;
    unsigned short* W1F = (unsigned short*)p;

    hipMemsetAsync(acc, 0, 3*Bb*8*sizeof(float), stream);
    wpack<<<(3*28*64 + 3*7*64 + 255)/256, 256, 0, stream>>>(
        W_phi2, W_phi1, b_phi1, b_phi2, W2F, W1F);

    enc_kernel<<<NBLK, 256, 0, stream>>>(
        X, W_enc1, b_enc1, W_enc2, b_enc2, W_enc3, b_enc3, g_enc, be_enc,
        W_agg, avail, XeBF, acc);

    phi_mfma<false><<<NBLK, 256, 0, stream>>>(
        XeBF, XeBF, Zb, acc, b_agg, W_agg + Ee*Hh, acc + Bb*8, avail,
        W1F, W2F, g_phi, be_phi, W_proj, b_proj, out);

    phi_mfma<false><<<NBLK, 256, 0, stream>>>(
        Zb, XeBF, Zb, acc + Bb*8, b_agg + Hh, W_agg + 2*Ee*Hh, acc + 2*Bb*8, avail,
        W1F + (size_t)7*512, W2F + (size_t)28*512,
        g_phi + EH, be_phi + EH, W_proj, b_proj, out);

    phi_mfma<true><<<NBLK, 256, 0, stream>>>(
        Zb, XeBF, Zb, acc + 2*Bb*8, b_agg + 2*Hh, W_agg, acc, avail,
        W1F + (size_t)14*512, W2F + (size_t)56*512,
        g_phi + 2*EH, be_phi + 2*EH, W_proj, b_proj, out);
}

// Round 6
// 286.871 us; speedup vs baseline: 1.1929x; 1.1929x over previous
//
#include <hip/hip_runtime.h>
#include <hip/hip_bf16.h>

#define Bb 128
#define Nn 4096
#define Ff 32
#define Ee 16
#define Hh 7
#define EH 112
#define NROW (Bb*Nn)
#define NBLK 2048           // phi/enc blocks: 256 rows each

typedef __attribute__((ext_vector_type(8))) short  bf16x8;
typedef __attribute__((ext_vector_type(4))) float  f32x4;
typedef __attribute__((ext_vector_type(4))) unsigned int u32x4;
typedef __attribute__((ext_vector_type(2))) unsigned int u32x2;

__device__ inline unsigned pack2(float a, float b) {
    __hip_bfloat162 h = __float22bfloat162_rn(make_float2(a, b));
    return *reinterpret_cast<unsigned*>(&h);
}
union BF8 { unsigned u[4]; bf16x8 v; u32x4 q; };

// ---------------------------------------------------------------- encoder ---
__global__ __launch_bounds__(256) void enc_kernel(
    const float* __restrict__ X,
    const float* __restrict__ W1, const float* __restrict__ b1,
    const float* __restrict__ W2, const float* __restrict__ b2,
    const float* __restrict__ W3, const float* __restrict__ b3,
    const float* __restrict__ g,  const float* __restrict__ be,
    const float* __restrict__ Wagg0, const int* __restrict__ avail,
    unsigned short* __restrict__ XeBF, float* __restrict__ acc0)
{
    __shared__ float sW1[Ff*Ee], sW2[Ee*Ee], sW3[Ee*Ee];
    __shared__ float sb1[Ee], sb2[Ee], sb3[Ee], sg[Ee], sbe[Ee];
    __shared__ float sWq[Ee*Hh];
    __shared__ float red[256][8];
    int tid = threadIdx.x;
    for (int i = tid; i < Ff*Ee; i += 256) sW1[i] = W1[i];
    for (int i = tid; i < Ee*Ee; i += 256) { sW2[i] = W2[i]; sW3[i] = W3[i]; }
    if (tid < Ee) { sb1[tid]=b1[tid]; sb2[tid]=b2[tid]; sb3[tid]=b3[tid];
                    sg[tid]=g[tid];   sbe[tid]=be[tid]; }
    if (tid < Ee*Hh) sWq[tid] = Wagg0[tid];
    __syncthreads();

    size_t row = (size_t)blockIdx.x * 256u + (unsigned)tid;
    const float4* xr = reinterpret_cast<const float4*>(X + row * Ff);
    float x[Ff];
    #pragma unroll
    for (int i = 0; i < Ff/4; ++i) {
        float4 v = xr[i];
        x[4*i+0]=v.x; x[4*i+1]=v.y; x[4*i+2]=v.z; x[4*i+3]=v.w;
    }
    float h1[Ee];
    #pragma unroll
    for (int e = 0; e < Ee; ++e) h1[e] = sb1[e];
    #pragma unroll 4
    for (int k = 0; k < Ff; ++k) {
        float xk = x[k];
        #pragma unroll
        for (int e = 0; e < Ee; ++e) h1[e] = fmaf(xk, sW1[k*Ee+e], h1[e]);
    }
    #pragma unroll
    for (int e = 0; e < Ee; ++e) h1[e] = fmaxf(h1[e], 0.f);

    float h2[Ee];
    #pragma unroll
    for (int e = 0; e < Ee; ++e) h2[e] = sb2[e];
    #pragma unroll 4
    for (int k = 0; k < Ee; ++k) {
        float hk = h1[k];
        #pragma unroll
        for (int e = 0; e < Ee; ++e) h2[e] = fmaf(hk, sW2[k*Ee+e], h2[e]);
    }
    #pragma unroll
    for (int e = 0; e < Ee; ++e) h2[e] = fmaxf(h2[e], 0.f);

    float z[Ee];
    #pragma unroll
    for (int e = 0; e < Ee; ++e) z[e] = sb3[e];
    #pragma unroll 4
    for (int k = 0; k < Ee; ++k) {
        float hk = h2[k];
        #pragma unroll
        for (int e = 0; e < Ee; ++e) z[e] = fmaf(hk, sW3[k*Ee+e], z[e]);
    }
    float m = 0.f;
    #pragma unroll
    for (int e = 0; e < Ee; ++e) m += z[e];
    m *= (1.f/Ee);
    float v = 0.f;
    #pragma unroll
    for (int e = 0; e < Ee; ++e) { float d = z[e]-m; v += d*d; }
    v *= (1.f/Ee);
    float inv = rsqrtf(v + 1e-6f);
    #pragma unroll
    for (int e = 0; e < Ee; ++e) z[e] = (z[e]-m)*inv*sg[e] + sbe[e];

    unsigned us[8];
    #pragma unroll
    for (int j = 0; j < 8; ++j) us[j] = pack2(z[2*j], z[2*j+1]);
    u32x4 lo = {us[0],us[1],us[2],us[3]};
    u32x4 hi = {us[4],us[5],us[6],us[7]};
    u32x4* xo = reinterpret_cast<u32x4*>(XeBF + row*Ee);
    xo[0] = lo; xo[1] = hi;

    // zbar_0 partials
    float af = (float)avail[row];
    float fc[Hh];
    #pragma unroll
    for (int h = 0; h < Hh; ++h) fc[h] = 0.f;
    #pragma unroll
    for (int e = 0; e < Ee; ++e) {
        float z2 = z[e]*z[e];
        #pragma unroll
        for (int h = 0; h < Hh; ++h) fc[h] = fmaf(z2, sWq[e*Hh+h], fc[h]);
    }
    #pragma unroll
    for (int h = 0; h < Hh; ++h) red[tid][h] = af * fc[h];
    red[tid][7] = af;
    __syncthreads();
    for (int s = 128; s > 0; s >>= 1) {
        if (tid < s) {
            #pragma unroll
            for (int q2 = 0; q2 < 8; ++q2) red[tid][q2] += red[tid+s][q2];
        }
        __syncthreads();
    }
    if (tid < 8) atomicAdd(&acc0[(blockIdx.x >> 4)*8 + tid], red[0][tid]);
}

// -------------------------------------------------- weight fragment packer --
// Biases folded into the K-pad: W1F k=16 row = b1; W2F k=112 row = b2.
__global__ __launch_bounds__(256) void wpack(
    const float* __restrict__ W_phi2, const float* __restrict__ W_phi1,
    const float* __restrict__ b_phi1, const float* __restrict__ b_phi2,
    unsigned short* __restrict__ W2F, unsigned short* __restrict__ W1F)
{
    int idx = blockIdx.x*256 + threadIdx.x;
    if (idx < 3*28*64) {
        int d = idx / (28*64); int r = idx % (28*64);
        int f = r >> 6, l = r & 63;
        int lg = l >> 4, li = l & 15, mt = f >> 2, kt = f & 3;
        const float* W2g = W_phi2 + (size_t)d*EH*EH;
        const float* b2g = b_phi2 + (size_t)d*EH;
        int mm = mt*16 + li;
        unsigned v[4];
        #pragma unroll
        for (int jj = 0; jj < 4; ++jj) {
            int k0 = kt*32 + lg*8 + jj*2;
            float a = (k0 < EH) ? W2g[(size_t)k0*EH + mm]
                                : (k0 == EH ? b2g[mm] : 0.f);
            float c = (k0+1 < EH) ? W2g[(size_t)(k0+1)*EH + mm] : 0.f;
            v[jj] = pack2(a, c);
        }
        u32x4 q = {v[0], v[1], v[2], v[3]};
        *reinterpret_cast<u32x4*>(W2F + (size_t)idx*8) = q;
    } else if (idx < 3*28*64 + 3*7*64) {
        int r2 = idx - 3*28*64;
        int d = r2 / (7*64); int r = r2 % (7*64);
        int mt = r >> 6, l = r & 63;
        int g = l >> 4, i = l & 15;
        const float* W1g = W_phi1 + (size_t)d*Ee*EH;
        const float* b1g = b_phi1 + (size_t)d*EH;
        int mm = mt*16 + i;
        unsigned v[4];
        #pragma unroll
        for (int jj = 0; jj < 4; ++jj) {
            float a = 0.f, c = 0.f;
            if (g < 2) {
                a = W1g[(size_t)(g*8 + jj*2)  *EH + mm];
                c = W1g[(size_t)(g*8 + jj*2+1)*EH + mm];
            } else if (g == 2 && jj == 0) {
                a = b1g[mm];                    // k=16 bias row
            }
            v[jj] = pack2(a, c);
        }
        u32x4 q = {v[0], v[1], v[2], v[3]};
        *reinterpret_cast<u32x4*>(W1F + (size_t)r2*8) = q;
    }
}

// ------------------------------------- phi via MFMA + fused zbar (+proj) ----
// LDS: sP1 only (XOR-swizzled, PS=128). W1/W2 fragments stream from global
// (L1/L2-resident, 28 KB). Plain loads everywhere -> L3 serves the streams.
template<bool LAST>
__global__ __launch_bounds__(256, 4) void phi_mfma(
    const unsigned short* __restrict__ Zin,   // bf16 [NROW][16]
    const unsigned short* __restrict__ Xe,    // bf16 [NROW][16]
    unsigned short* __restrict__ Zout,
    const float* __restrict__ accIn, const float* __restrict__ baggD,
    const float* __restrict__ WaggN, float* __restrict__ accN,
    const int* __restrict__ avail,
    const unsigned short* __restrict__ W1F,   // packed A-frags [7][64][8]
    const unsigned short* __restrict__ W2F,   // packed A-frags [28][64][8]
    const float* __restrict__ gg,  const float* __restrict__ beg,
    const float* __restrict__ Wp,  const float* __restrict__ bp,
    float* __restrict__ out)
{
    __shared__ __align__(16) unsigned short sP1[4][2][16*128];  // 32 KB
    __shared__ __align__(16) float sGZ[EH];

    int tid  = threadIdx.x;
    int wave = tid >> 6, lane = tid & 63;
    int g = lane >> 4, i = lane & 15;
    int i7 = i & 7;

    // zero sP1 (cols 112..127 stay {1.0-col, zeros} forever)
    for (int p = tid; p < (4*2*16*128)/8; p += 256) {
        u32x4 zq = {0u,0u,0u,0u};
        reinterpret_cast<u32x4*>(&sP1[0][0][0])[p] = zq;
    }

    int b = blockIdx.x >> 4;                     // 16 blocks per batch
    float cntb = accIn[b*8 + 7];
    float cden = fmaxf(cntb, 1.f);
    float zb[Hh];
    #pragma unroll
    for (int h = 0; h < Hh; ++h)
        zb[h] = (accIn[b*8 + h] + baggD[h]*cntb) / cden * (1.f/Hh);
    if (tid < EH) sGZ[tid] = gg[tid] * zb[tid >> 4];
    __syncthreads();

    // ones column at col 112 (16B-block 14), both buffers of this wave
    if (g == 0) {
        int idx = i*128 + ((14 ^ i7) << 3);
        sP1[wave][0][idx] = 0x3F80;
        sP1[wave][1][idx] = 0x3F80;
    }

    float Gz[4] = {0,0,0,0}, Bz[4] = {0,0,0,0};
    #pragma unroll
    for (int mt = 0; mt < 7; ++mt) {
        f32x4 gv = *reinterpret_cast<const f32x4*>(&sGZ[mt*16 + 4*g]);
        f32x4 bv = *reinterpret_cast<const f32x4*>(beg + mt*16 + 4*g);
        #pragma unroll
        for (int r = 0; r < 4; ++r) { Gz[r] += gv[r]; Bz[r] += bv[r]*zb[mt]; }
    }
    float wpa[4] = {0,0,0,0}, wpb[4] = {0,0,0,0}, bp0 = 0.f, bp1 = 0.f;
    if (LAST) {
        f32x4 u0 = *reinterpret_cast<const f32x4*>(Wp + 8*g);
        f32x4 u1 = *reinterpret_cast<const f32x4*>(Wp + 8*g + 4);
        wpa[0]=u0[0]; wpa[1]=u0[2]; wpa[2]=u1[0]; wpa[3]=u1[2];
        wpb[0]=u0[1]; wpb[1]=u0[3]; wpb[2]=u1[1]; wpb[3]=u1[3];
        bp0 = bp[0]; bp1 = bp[1];
    }
    float wacc2[4] = {0,0,0,0};
    float wcnt = 0.f;

    size_t r0 = (size_t)(blockIdx.x*16 + wave*4) * 16;
    unsigned short* p1A = &sP1[wave][0][0];
    unsigned short* p1B = &sP1[wave][1][0];
    const f32x4 zz = {0.f,0.f,0.f,0.f};

    auto epi = [&](const f32x4 (&d2)[7], u32x2 zu, size_t row0, float af) {
        // moments (independent reduce chains)
        float s = 0.f, q = 0.f;
        #pragma unroll
        for (int mt = 0; mt < 7; ++mt) {
            #pragma unroll
            for (int r = 0; r < 4; ++r) { float v = d2[mt][r]; s += v; q = fmaf(v,v,q); }
        }
        s += __shfl_xor(s, 16); q += __shfl_xor(q, 16);
        s += __shfl_xor(s, 32); q += __shfl_xor(q, 32);
        float m = s * (1.f/EH);
        float var = fmaf(-m, m, q * (1.f/EH));
        float inv = rsqrtf(var + 1e-6f);

        float S1[4] = {0,0,0,0};
        #pragma unroll
        for (int mt = 0; mt < 7; ++mt) {
            f32x4 gv = *reinterpret_cast<const f32x4*>(&sGZ[mt*16 + 4*g]);
            #pragma unroll
            for (int r = 0; r < 4; ++r) S1[r] = fmaf(d2[mt][r], gv[r], S1[r]);
        }
        unsigned lo = zu[0], hi = zu[1];
        float zv[4];
        zv[0] = __uint_as_float((lo & 0xFFFFu) << 16);
        zv[1] = __uint_as_float(lo & 0xFFFF0000u);
        zv[2] = __uint_as_float((hi & 0xFFFFu) << 16);
        zv[3] = __uint_as_float(hi & 0xFFFF0000u);
        float zn[4];
        #pragma unroll
        for (int r = 0; r < 4; ++r)
            zn[r] = zv[r] + fmaf(-m, Gz[r], S1[r]) * inv + Bz[r];

        if (!LAST) {
            u32x2 w = {pack2(zn[0], zn[1]), pack2(zn[2], zn[3])};
            *reinterpret_cast<u32x2*>(Zout + (row0 + i)*Ee + 4*g) = w;
            #pragma unroll
            for (int r = 0; r < 4; ++r) wacc2[r] = fmaf(af, zn[r]*zn[r], wacc2[r]);
            wcnt += af;
        } else {
            float o0 = zn[0]*wpa[0] + zn[1]*wpa[1] + zn[2]*wpa[2] + zn[3]*wpa[3];
            float o1 = zn[0]*wpb[0] + zn[1]*wpb[1] + zn[2]*wpb[2] + zn[3]*wpb[3];
            o0 += __shfl_xor(o0, 16); o0 += __shfl_xor(o0, 32);
            o1 += __shfl_xor(o1, 16); o1 += __shfl_xor(o1, 32);
            if (g == 0) {
                float2 o; o.x = o0 + bp0; o.y = o1 + bp1;
                *reinterpret_cast<float2*>(out + (row0 + i)*2) = o;
            }
        }
    };

    auto pair = [&](bf16x8 bxA, bf16x8 bxB, size_t rowA) {
        // issue stream loads early; MFMA/LDS work below covers them
        u32x2 zuA = *reinterpret_cast<const u32x2*>(Zin + (rowA + i)*Ee + 4*g);
        u32x2 zuB = *reinterpret_cast<const u32x2*>(Zin + (rowA + 16 + i)*Ee + 4*g);
        float afA = 0.f, afB = 0.f;
        if (!LAST) {
            afA = (float)avail[rowA + i];
            afB = (float)avail[rowA + 16 + i];
        }
        // W1 A-frags from global (L1-hot)
        bf16x8 aW1[7];
        #pragma unroll
        for (int mt = 0; mt < 7; ++mt)
            aW1[mt] = *reinterpret_cast<const bf16x8*>(W1F + (size_t)(mt*64 + lane)*8);
        // phi1 both tiles, pack, swizzled LDS store
        #pragma unroll
        for (int mt = 0; mt < 7; ++mt) {
            f32x4 dA = __builtin_amdgcn_mfma_f32_16x16x32_bf16(aW1[mt], bxA, zz, 0,0,0);
            f32x4 dB = __builtin_amdgcn_mfma_f32_16x16x32_bf16(aW1[mt], bxB, zz, 0,0,0);
            #pragma unroll
            for (int r = 0; r < 4; ++r) { dA[r] = fmaxf(dA[r],0.f); dB[r] = fmaxf(dB[r],0.f); }
            u32x2 wA = {pack2(dA[0],dA[1]), pack2(dA[2],dA[3])};
            u32x2 wB = {pack2(dB[0],dB[1]), pack2(dB[2],dB[3])};
            int widx = i*128 + (((2*mt + (g>>1)) ^ i7) << 3) + ((g&1) << 2);
            *reinterpret_cast<u32x2*>(&p1A[widx]) = wA;
            *reinterpret_cast<u32x2*>(&p1B[widx]) = wB;
        }
        // phi2 both tiles; W2 A-frags from global (L1-hot), shared across pair
        f32x4 d2A[7], d2B[7];
        #pragma unroll
        for (int mt = 0; mt < 7; ++mt) { d2A[mt] = zz; d2B[mt] = zz; }
        #pragma unroll
        for (int kt = 0; kt < 4; ++kt) {
            int ridx = i*128 + (((4*kt + g) ^ i7) << 3);
            bf16x8 bpA = *reinterpret_cast<const bf16x8*>(&p1A[ridx]);
            bf16x8 bpB = *reinterpret_cast<const bf16x8*>(&p1B[ridx]);
            #pragma unroll
            for (int mt = 0; mt < 7; ++mt) {
                bf16x8 a = *reinterpret_cast<const bf16x8*>(
                    W2F + (size_t)((mt*4 + kt)*64 + lane)*8);
                d2A[mt] = __builtin_amdgcn_mfma_f32_16x16x32_bf16(a, bpA, d2A[mt], 0,0,0);
                d2B[mt] = __builtin_amdgcn_mfma_f32_16x16x32_bf16(a, bpB, d2B[mt], 0,0,0);
            }
        }
        epi(d2A, zuA, rowA, afA);
        epi(d2B, zuB, rowA + 16, afB);
    };

    // B-frags for all 4 tiles up-front (g=2 carries 1.0 at k=16 for bias row)
    BF8 bz_; bz_.u[0]=bz_.u[1]=bz_.u[2]=bz_.u[3]=0u;
    if (g == 2) bz_.u[0] = 0x00003F80u;
    bf16x8 bx0 = bz_.v, bx1 = bz_.v, bx2 = bz_.v, bx3 = bz_.v;
    if (g < 2) {
        const unsigned short* xp = Xe + (r0 + i)*Ee + g*8;
        bx0 = *reinterpret_cast<const bf16x8*>(xp);
        bx1 = *reinterpret_cast<const bf16x8*>(xp + 16*Ee);
        bx2 = *reinterpret_cast<const bf16x8*>(xp + 32*Ee);
        bx3 = *reinterpret_cast<const bf16x8*>(xp + 48*Ee);
    }

    pair(bx0, bx1, r0);
    pair(bx2, bx3, r0 + 32);

    if (!LAST) {
        // deferred zbar contraction + wave reduce
        float f[Hh];
        #pragma unroll
        for (int h = 0; h < Hh; ++h) {
            float a = 0.f;
            #pragma unroll
            for (int r = 0; r < 4; ++r)
                a = fmaf(WaggN[(4*g + r)*Hh + h], wacc2[r], a);
            f[h] = a;
        }
        #pragma unroll
        for (int off = 1; off < 64; off <<= 1) {
            #pragma unroll
            for (int h = 0; h < Hh; ++h) f[h] += __shfl_xor(f[h], off);
            wcnt += __shfl_xor(wcnt, off);
        }
        if (lane == 0) {
            #pragma unroll
            for (int h = 0; h < Hh; ++h) atomicAdd(&accN[b*8 + h], f[h]);
            atomicAdd(&accN[b*8 + 7], wcnt * 0.25f);
        }
    }
}

// ---------------------------------------------------------------- launcher --
extern "C" void kernel_launch(void* const* d_in, const int* in_sizes, int n_in,
                              void* d_out, int out_size, void* d_ws, size_t ws_size,
                              hipStream_t stream)
{
    const float* X      = (const float*)d_in[0];
    const int*   avail  = (const int*)  d_in[1];
    const float* W_enc1 = (const float*)d_in[2];  const float* b_enc1 = (const float*)d_in[3];
    const float* W_enc2 = (const float*)d_in[4];  const float* b_enc2 = (const float*)d_in[5];
    const float* W_enc3 = (const float*)d_in[6];  const float* b_enc3 = (const float*)d_in[7];
    const float* g_enc  = (const float*)d_in[8];  const float* be_enc = (const float*)d_in[9];
    const float* W_agg  = (const float*)d_in[10]; const float* b_agg  = (const float*)d_in[11];
    const float* W_phi1 = (const float*)d_in[12]; const float* b_phi1 = (const float*)d_in[13];
    const float* W_phi2 = (const float*)d_in[14]; const float* b_phi2 = (const float*)d_in[15];
    const float* g_phi  = (const float*)d_in[16]; const float* be_phi = (const float*)d_in[17];
    const float* W_proj = (const float*)d_in[18]; const float* b_proj = (const float*)d_in[19];
    float* out = (float*)d_out;

    char* ws = (char*)d_ws;
    unsigned short* XeBF = (unsigned short*)ws;                        // 16 MiB
    unsigned short* Zb   = (unsigned short*)(ws + (size_t)NROW*Ee*2);  // 16 MiB
    char* p = ws + 2*(size_t)NROW*Ee*2;
    float* acc = (float*)p;                  p += 3*Bb*8*sizeof(float);
    unsigned short* W2F = (unsigned short*)p; p += (size_t)3*28*512*2;
    unsigned short* W1F = (unsigned short*)p;

    hipMemsetAsync(acc, 0, 3*Bb*8*sizeof(float), stream);
    wpack<<<(3*28*64 + 3*7*64 + 255)/256, 256, 0, stream>>>(
        W_phi2, W_phi1, b_phi1, b_phi2, W2F, W1F);

    enc_kernel<<<NBLK, 256, 0, stream>>>(
        X, W_enc1, b_enc1, W_enc2, b_enc2, W_enc3, b_enc3, g_enc, be_enc,
        W_agg, avail, XeBF, acc);

    phi_mfma<false><<<NBLK, 256, 0, stream>>>(
        XeBF, XeBF, Zb, acc, b_agg, W_agg + Ee*Hh, acc + Bb*8, avail,
        W1F, W2F, g_phi, be_phi, W_proj, b_proj, out);

    phi_mfma<false><<<NBLK, 256, 0, stream>>>(
        Zb, XeBF, Zb, acc + Bb*8, b_agg + Hh, W_agg + 2*Ee*Hh, acc + 2*Bb*8, avail,
        W1F + (size_t)7*512, W2F + (size_t)28*512,
        g_phi + EH, be_phi + EH, W_proj, b_proj, out);

    phi_mfma<true><<<NBLK, 256, 0, stream>>>(
        Zb, XeBF, Zb, acc + 2*Bb*8, b_agg + 2*Hh, W_agg, acc, avail,
        W1F + (size_t)14*512, W2F + (size_t)56*512,
        g_phi + 2*EH, be_phi + 2*EH, W_proj, b_proj, out);
}

// Round 7
// 227.537 us; speedup vs baseline: 1.5039x; 1.2608x over previous
//
#include <hip/hip_runtime.h>
#include <hip/hip_bf16.h>

#define Bb 128
#define Nn 4096
#define Ff 32
#define Ee 16
#define Hh 7
#define EH 112
#define NROW (Bb*Nn)
#define NBLK 2048           // phi/enc blocks: 256 rows each

typedef __attribute__((ext_vector_type(8))) short  bf16x8;
typedef __attribute__((ext_vector_type(4))) float  f32x4;
typedef __attribute__((ext_vector_type(4))) unsigned int u32x4;
typedef __attribute__((ext_vector_type(2))) unsigned int u32x2;

__device__ inline unsigned pack2(float a, float b) {
    __hip_bfloat162 h = __float22bfloat162_rn(make_float2(a, b));
    return *reinterpret_cast<unsigned*>(&h);
}
union BF8 { unsigned u[4]; bf16x8 v; u32x4 q; };

// ---------------------------------------------------------------- encoder ---
__global__ __launch_bounds__(256) void enc_kernel(
    const float* __restrict__ X,
    const float* __restrict__ W1, const float* __restrict__ b1,
    const float* __restrict__ W2, const float* __restrict__ b2,
    const float* __restrict__ W3, const float* __restrict__ b3,
    const float* __restrict__ g,  const float* __restrict__ be,
    const float* __restrict__ Wagg0, const int* __restrict__ avail,
    unsigned short* __restrict__ XeBF, float* __restrict__ acc0)
{
    __shared__ float sW1[Ff*Ee], sW2[Ee*Ee], sW3[Ee*Ee];
    __shared__ float sb1[Ee], sb2[Ee], sb3[Ee], sg[Ee], sbe[Ee];
    __shared__ float sWq[Ee*Hh];
    __shared__ float red[256][8];
    int tid = threadIdx.x;
    for (int i = tid; i < Ff*Ee; i += 256) sW1[i] = W1[i];
    for (int i = tid; i < Ee*Ee; i += 256) { sW2[i] = W2[i]; sW3[i] = W3[i]; }
    if (tid < Ee) { sb1[tid]=b1[tid]; sb2[tid]=b2[tid]; sb3[tid]=b3[tid];
                    sg[tid]=g[tid];   sbe[tid]=be[tid]; }
    if (tid < Ee*Hh) sWq[tid] = Wagg0[tid];
    __syncthreads();

    size_t row = (size_t)blockIdx.x * 256u + (unsigned)tid;
    const float4* xr = reinterpret_cast<const float4*>(X + row * Ff);
    float x[Ff];
    #pragma unroll
    for (int i = 0; i < Ff/4; ++i) {
        float4 v = xr[i];
        x[4*i+0]=v.x; x[4*i+1]=v.y; x[4*i+2]=v.z; x[4*i+3]=v.w;
    }
    float h1[Ee];
    #pragma unroll
    for (int e = 0; e < Ee; ++e) h1[e] = sb1[e];
    #pragma unroll 4
    for (int k = 0; k < Ff; ++k) {
        float xk = x[k];
        #pragma unroll
        for (int e = 0; e < Ee; ++e) h1[e] = fmaf(xk, sW1[k*Ee+e], h1[e]);
    }
    #pragma unroll
    for (int e = 0; e < Ee; ++e) h1[e] = fmaxf(h1[e], 0.f);

    float h2[Ee];
    #pragma unroll
    for (int e = 0; e < Ee; ++e) h2[e] = sb2[e];
    #pragma unroll 4
    for (int k = 0; k < Ee; ++k) {
        float hk = h1[k];
        #pragma unroll
        for (int e = 0; e < Ee; ++e) h2[e] = fmaf(hk, sW2[k*Ee+e], h2[e]);
    }
    #pragma unroll
    for (int e = 0; e < Ee; ++e) h2[e] = fmaxf(h2[e], 0.f);

    float z[Ee];
    #pragma unroll
    for (int e = 0; e < Ee; ++e) z[e] = sb3[e];
    #pragma unroll 4
    for (int k = 0; k < Ee; ++k) {
        float hk = h2[k];
        #pragma unroll
        for (int e = 0; e < Ee; ++e) z[e] = fmaf(hk, sW3[k*Ee+e], z[e]);
    }
    float m = 0.f;
    #pragma unroll
    for (int e = 0; e < Ee; ++e) m += z[e];
    m *= (1.f/Ee);
    float v = 0.f;
    #pragma unroll
    for (int e = 0; e < Ee; ++e) { float d = z[e]-m; v += d*d; }
    v *= (1.f/Ee);
    float inv = rsqrtf(v + 1e-6f);
    #pragma unroll
    for (int e = 0; e < Ee; ++e) z[e] = (z[e]-m)*inv*sg[e] + sbe[e];

    unsigned us[8];
    #pragma unroll
    for (int j = 0; j < 8; ++j) us[j] = pack2(z[2*j], z[2*j+1]);
    u32x4 lo = {us[0],us[1],us[2],us[3]};
    u32x4 hi = {us[4],us[5],us[6],us[7]};
    u32x4* xo = reinterpret_cast<u32x4*>(XeBF + row*Ee);
    xo[0] = lo; xo[1] = hi;

    // zbar_0 partials
    float af = (float)avail[row];
    float fc[Hh];
    #pragma unroll
    for (int h = 0; h < Hh; ++h) fc[h] = 0.f;
    #pragma unroll
    for (int e = 0; e < Ee; ++e) {
        float z2 = z[e]*z[e];
        #pragma unroll
        for (int h = 0; h < Hh; ++h) fc[h] = fmaf(z2, sWq[e*Hh+h], fc[h]);
    }
    #pragma unroll
    for (int h = 0; h < Hh; ++h) red[tid][h] = af * fc[h];
    red[tid][7] = af;
    __syncthreads();
    for (int s = 128; s > 0; s >>= 1) {
        if (tid < s) {
            #pragma unroll
            for (int q2 = 0; q2 < 8; ++q2) red[tid][q2] += red[tid+s][q2];
        }
        __syncthreads();
    }
    if (tid < 8) atomicAdd(&acc0[(blockIdx.x >> 4)*8 + tid], red[0][tid]);
}

// -------------------------------------------------- weight fragment packer --
// W1F: standard k-order, k=16 row = b1 (bias via B-side 1.0 at k=16).
// W2F: PERMUTED k-order matching phi1's D-register layout:
//   within each kt block of 32, element t of lane-group lg maps to
//   k = kt*32 + (t>=4)*16 + 4*lg + (t&3).  k=112 row = b2.
__global__ __launch_bounds__(256) void wpack(
    const float* __restrict__ W_phi2, const float* __restrict__ W_phi1,
    const float* __restrict__ b_phi1, const float* __restrict__ b_phi2,
    unsigned short* __restrict__ W2F, unsigned short* __restrict__ W1F)
{
    int idx = blockIdx.x*256 + threadIdx.x;
    if (idx < 3*28*64) {
        int d = idx / (28*64); int r = idx % (28*64);
        int f = r >> 6, l = r & 63;
        int lg = l >> 4, li = l & 15, mt = f >> 2, kt = f & 3;
        const float* W2g = W_phi2 + (size_t)d*EH*EH;
        const float* b2g = b_phi2 + (size_t)d*EH;
        int mm = mt*16 + li;
        unsigned v[4];
        #pragma unroll
        for (int jj = 0; jj < 4; ++jj) {
            int t0 = 2*jj, t1 = 2*jj + 1;
            int k0 = kt*32 + ((t0 >> 2) << 4) + 4*lg + (t0 & 3);
            int k1 = kt*32 + ((t1 >> 2) << 4) + 4*lg + (t1 & 3);
            float a = (k0 < EH) ? W2g[(size_t)k0*EH + mm]
                                : (k0 == EH ? b2g[mm] : 0.f);
            float c = (k1 < EH) ? W2g[(size_t)k1*EH + mm]
                                : (k1 == EH ? b2g[mm] : 0.f);
            v[jj] = pack2(a, c);
        }
        u32x4 q = {v[0], v[1], v[2], v[3]};
        *reinterpret_cast<u32x4*>(W2F + (size_t)idx*8) = q;
    } else if (idx < 3*28*64 + 3*7*64) {
        int r2 = idx - 3*28*64;
        int d = r2 / (7*64); int r = r2 % (7*64);
        int mt = r >> 6, l = r & 63;
        int g = l >> 4, i = l & 15;
        const float* W1g = W_phi1 + (size_t)d*Ee*EH;
        const float* b1g = b_phi1 + (size_t)d*EH;
        int mm = mt*16 + i;
        unsigned v[4];
        #pragma unroll
        for (int jj = 0; jj < 4; ++jj) {
            float a = 0.f, c = 0.f;
            if (g < 2) {
                a = W1g[(size_t)(g*8 + jj*2)  *EH + mm];
                c = W1g[(size_t)(g*8 + jj*2+1)*EH + mm];
            } else if (g == 2 && jj == 0) {
                a = b1g[mm];                    // k=16 bias row
            }
            v[jj] = pack2(a, c);
        }
        u32x4 q = {v[0], v[1], v[2], v[3]};
        *reinterpret_cast<u32x4*>(W1F + (size_t)r2*8) = q;
    }
}

// ------------------------------------- phi via MFMA + fused zbar (+proj) ----
// phi1 D-regs feed phi2 B-operand DIRECTLY (k-permutation folded into W2F).
// LDS: staged sW2F (28 KB) + sGZ only. No P1 buffer, no shuffles for handoff.
template<bool LAST>
__global__ __launch_bounds__(256, 3) void phi_mfma(
    const unsigned short* __restrict__ Zin,   // bf16 [NROW][16]
    const unsigned short* __restrict__ Xe,    // bf16 [NROW][16]
    unsigned short* __restrict__ Zout,
    const float* __restrict__ accIn, const float* __restrict__ baggD,
    const float* __restrict__ WaggN, float* __restrict__ accN,
    const int* __restrict__ avail,
    const unsigned short* __restrict__ W1F,   // packed A-frags [7][64][8]
    const unsigned short* __restrict__ W2F,   // packed A-frags [28][64][8], permuted k
    const float* __restrict__ gg,  const float* __restrict__ beg,
    const float* __restrict__ Wp,  const float* __restrict__ bp,
    float* __restrict__ out)
{
    __shared__ __align__(16) unsigned short sW2F[28*512];   // 28 KB
    __shared__ __align__(16) float sGZ[EH];

    int tid  = threadIdx.x;
    int wave = tid >> 6, lane = tid & 63;
    int g = lane >> 4, i = lane & 15;

    // stage pre-packed W2 fragments (coalesced)
    for (int p = tid; p < 28*64; p += 256)
        *reinterpret_cast<u32x4*>(&sW2F[p*8]) =
            *reinterpret_cast<const u32x4*>(W2F + (size_t)p*8);

    int b = blockIdx.x >> 4;                     // 16 blocks per batch
    float cntb = accIn[b*8 + 7];
    float cden = fmaxf(cntb, 1.f);
    float zb[Hh];
    #pragma unroll
    for (int h = 0; h < Hh; ++h)
        zb[h] = (accIn[b*8 + h] + baggD[h]*cntb) / cden * (1.f/Hh);
    if (tid < EH) sGZ[tid] = gg[tid] * zb[tid >> 4];
    __syncthreads();

    float Gz[4] = {0,0,0,0}, Bz[4] = {0,0,0,0};
    #pragma unroll
    for (int mt = 0; mt < 7; ++mt) {
        f32x4 gv = *reinterpret_cast<const f32x4*>(&sGZ[mt*16 + 4*g]);
        f32x4 bv = *reinterpret_cast<const f32x4*>(beg + mt*16 + 4*g);
        #pragma unroll
        for (int r = 0; r < 4; ++r) { Gz[r] += gv[r]; Bz[r] += bv[r]*zb[mt]; }
    }
    float wpa[4] = {0,0,0,0}, wpb[4] = {0,0,0,0}, bp0 = 0.f, bp1 = 0.f;
    if (LAST) {
        f32x4 u0 = *reinterpret_cast<const f32x4*>(Wp + 8*g);
        f32x4 u1 = *reinterpret_cast<const f32x4*>(Wp + 8*g + 4);
        wpa[0]=u0[0]; wpa[1]=u0[2]; wpa[2]=u1[0]; wpa[3]=u1[2];
        wpb[0]=u0[1]; wpb[1]=u0[3]; wpb[2]=u1[1]; wpb[3]=u1[3];
        bp0 = bp[0]; bp1 = bp[1];
    }
    // W1 A-frags (held in registers for the whole kernel)
    bf16x8 aW1[7];
    #pragma unroll
    for (int mt = 0; mt < 7; ++mt)
        aW1[mt] = *reinterpret_cast<const bf16x8*>(W1F + (size_t)(mt*64 + lane)*8);

    float wacc2[4] = {0,0,0,0};
    float wcnt = 0.f;

    size_t r0 = (size_t)(blockIdx.x*16 + wave*4) * 16;
    const f32x4 zz = {0.f,0.f,0.f,0.f};
    const unsigned oneu = (g == 0) ? 0x00003F80u : 0u;   // bf16(1.0) at j=112

    auto epi = [&](const f32x4 (&d2)[7], u32x2 zu, size_t row0, float af) {
        float s = 0.f, q = 0.f;
        #pragma unroll
        for (int mt = 0; mt < 7; ++mt) {
            #pragma unroll
            for (int r = 0; r < 4; ++r) { float v = d2[mt][r]; s += v; q = fmaf(v,v,q); }
        }
        s += __shfl_xor(s, 16); q += __shfl_xor(q, 16);
        s += __shfl_xor(s, 32); q += __shfl_xor(q, 32);
        float m = s * (1.f/EH);
        float var = fmaf(-m, m, q * (1.f/EH));
        float inv = rsqrtf(var + 1e-6f);

        float S1[4] = {0,0,0,0};
        #pragma unroll
        for (int mt = 0; mt < 7; ++mt) {
            f32x4 gv = *reinterpret_cast<const f32x4*>(&sGZ[mt*16 + 4*g]);
            #pragma unroll
            for (int r = 0; r < 4; ++r) S1[r] = fmaf(d2[mt][r], gv[r], S1[r]);
        }
        unsigned lo = zu[0], hi = zu[1];
        float zv[4];
        zv[0] = __uint_as_float((lo & 0xFFFFu) << 16);
        zv[1] = __uint_as_float(lo & 0xFFFF0000u);
        zv[2] = __uint_as_float((hi & 0xFFFFu) << 16);
        zv[3] = __uint_as_float(hi & 0xFFFF0000u);
        float zn[4];
        #pragma unroll
        for (int r = 0; r < 4; ++r)
            zn[r] = zv[r] + fmaf(-m, Gz[r], S1[r]) * inv + Bz[r];

        if (!LAST) {
            u32x2 w = {pack2(zn[0], zn[1]), pack2(zn[2], zn[3])};
            *reinterpret_cast<u32x2*>(Zout + (row0 + i)*Ee + 4*g) = w;
            #pragma unroll
            for (int r = 0; r < 4; ++r) wacc2[r] = fmaf(af, zn[r]*zn[r], wacc2[r]);
            wcnt += af;
        } else {
            float o0 = zn[0]*wpa[0] + zn[1]*wpa[1] + zn[2]*wpa[2] + zn[3]*wpa[3];
            float o1 = zn[0]*wpb[0] + zn[1]*wpb[1] + zn[2]*wpb[2] + zn[3]*wpb[3];
            o0 += __shfl_xor(o0, 16); o0 += __shfl_xor(o0, 32);
            o1 += __shfl_xor(o1, 16); o1 += __shfl_xor(o1, 32);
            if (g == 0) {
                float2 o; o.x = o0 + bp0; o.y = o1 + bp1;
                *reinterpret_cast<float2*>(out + (row0 + i)*2) = o;
            }
        }
    };

    auto pair = [&](size_t rowA) {
        // stream loads early (L2/L3-served); covered by MFMA below
        u32x2 zuA = *reinterpret_cast<const u32x2*>(Zin + (rowA + i)*Ee + 4*g);
        u32x2 zuB = *reinterpret_cast<const u32x2*>(Zin + (rowA + 16 + i)*Ee + 4*g);
        float afA = 0.f, afB = 0.f;
        if (!LAST) {
            afA = (float)avail[rowA + i];
            afB = (float)avail[rowA + 16 + i];
        }
        BF8 bz_; bz_.u[0]=bz_.u[1]=bz_.u[2]=bz_.u[3]=0u;
        if (g == 2) bz_.u[0] = 0x00003F80u;     // 1.0 at k=16 (phi1 bias row)
        bf16x8 bxA = bz_.v, bxB = bz_.v;
        if (g < 2) {
            bxA = *reinterpret_cast<const bf16x8*>(Xe + (rowA + i)*Ee + g*8);
            bxB = *reinterpret_cast<const bf16x8*>(Xe + (rowA + 16 + i)*Ee + g*8);
        }

        // ---- phi1: 7 MFMAs per tile, relu, pack to bf16 words in regs ----
        unsigned wA[14], wB[14];
        #pragma unroll
        for (int mt = 0; mt < 7; ++mt) {
            f32x4 dA = __builtin_amdgcn_mfma_f32_16x16x32_bf16(aW1[mt], bxA, zz, 0,0,0);
            f32x4 dB = __builtin_amdgcn_mfma_f32_16x16x32_bf16(aW1[mt], bxB, zz, 0,0,0);
            #pragma unroll
            for (int r = 0; r < 4; ++r) { dA[r] = fmaxf(dA[r],0.f); dB[r] = fmaxf(dB[r],0.f); }
            wA[2*mt]   = pack2(dA[0], dA[1]);
            wA[2*mt+1] = pack2(dA[2], dA[3]);
            wB[2*mt]   = pack2(dB[0], dB[1]);
            wB[2*mt+1] = pack2(dB[2], dB[3]);
        }

        // ---- phi2: B-frags straight from registers (permuted-k W2F) ----
        f32x4 d2A[7], d2B[7];
        #pragma unroll
        for (int mt = 0; mt < 7; ++mt) { d2A[mt] = zz; d2B[mt] = zz; }
        #pragma unroll
        for (int kt = 0; kt < 4; ++kt) {
            BF8 fA, fB;
            if (kt < 3) {
                fA.u[0]=wA[4*kt]; fA.u[1]=wA[4*kt+1]; fA.u[2]=wA[4*kt+2]; fA.u[3]=wA[4*kt+3];
                fB.u[0]=wB[4*kt]; fB.u[1]=wB[4*kt+1]; fB.u[2]=wB[4*kt+2]; fB.u[3]=wB[4*kt+3];
            } else {            // mt=6 pair + bias row (j=112 -> 1.0 on g==0)
                fA.u[0]=wA[12]; fA.u[1]=wA[13]; fA.u[2]=oneu; fA.u[3]=0u;
                fB.u[0]=wB[12]; fB.u[1]=wB[13]; fB.u[2]=oneu; fB.u[3]=0u;
            }
            #pragma unroll
            for (int mt = 0; mt < 7; ++mt) {
                bf16x8 a = *reinterpret_cast<const bf16x8*>(&sW2F[(mt*4 + kt)*512 + lane*8]);
                d2A[mt] = __builtin_amdgcn_mfma_f32_16x16x32_bf16(a, fA.v, d2A[mt], 0,0,0);
                d2B[mt] = __builtin_amdgcn_mfma_f32_16x16x32_bf16(a, fB.v, d2B[mt], 0,0,0);
            }
        }
        epi(d2A, zuA, rowA, afA);
        epi(d2B, zuB, rowA + 16, afB);
    };

    pair(r0);
    pair(r0 + 32);

    if (!LAST) {
        // deferred zbar contraction + wave reduce
        float f[Hh];
        #pragma unroll
        for (int h = 0; h < Hh; ++h) {
            float a = 0.f;
            #pragma unroll
            for (int r = 0; r < 4; ++r)
                a = fmaf(WaggN[(4*g + r)*Hh + h], wacc2[r], a);
            f[h] = a;
        }
        #pragma unroll
        for (int off = 1; off < 64; off <<= 1) {
            #pragma unroll
            for (int h = 0; h < Hh; ++h) f[h] += __shfl_xor(f[h], off);
            wcnt += __shfl_xor(wcnt, off);
        }
        if (lane == 0) {
            #pragma unroll
            for (int h = 0; h < Hh; ++h) atomicAdd(&accN[b*8 + h], f[h]);
            atomicAdd(&accN[b*8 + 7], wcnt * 0.25f);
        }
    }
}

// ---------------------------------------------------------------- launcher --
extern "C" void kernel_launch(void* const* d_in, const int* in_sizes, int n_in,
                              void* d_out, int out_size, void* d_ws, size_t ws_size,
                              hipStream_t stream)
{
    const float* X      = (const float*)d_in[0];
    const int*   avail  = (const int*)  d_in[1];
    const float* W_enc1 = (const float*)d_in[2];  const float* b_enc1 = (const float*)d_in[3];
    const float* W_enc2 = (const float*)d_in[4];  const float* b_enc2 = (const float*)d_in[5];
    const float* W_enc3 = (const float*)d_in[6];  const float* b_enc3 = (const float*)d_in[7];
    const float* g_enc  = (const float*)d_in[8];  const float* be_enc = (const float*)d_in[9];
    const float* W_agg  = (const float*)d_in[10]; const float* b_agg  = (const float*)d_in[11];
    const float* W_phi1 = (const float*)d_in[12]; const float* b_phi1 = (const float*)d_in[13];
    const float* W_phi2 = (const float*)d_in[14]; const float* b_phi2 = (const float*)d_in[15];
    const float* g_phi  = (const float*)d_in[16]; const float* be_phi = (const float*)d_in[17];
    const float* W_proj = (const float*)d_in[18]; const float* b_proj = (const float*)d_in[19];
    float* out = (float*)d_out;

    char* ws = (char*)d_ws;
    unsigned short* XeBF = (unsigned short*)ws;                        // 16 MiB
    unsigned short* Zb   = (unsigned short*)(ws + (size_t)NROW*Ee*2);  // 16 MiB
    char* p = ws + 2*(size_t)NROW*Ee*2;
    float* acc = (float*)p;                  p += 3*Bb*8*sizeof(float);
    unsigned short* W2F = (unsigned short*)p; p += (size_t)3*28*512*2;
    unsigned short* W1F = (unsigned short*)p;

    hipMemsetAsync(acc, 0, 3*Bb*8*sizeof(float), stream);
    wpack<<<(3*28*64 + 3*7*64 + 255)/256, 256, 0, stream>>>(
        W_phi2, W_phi1, b_phi1, b_phi2, W2F, W1F);

    enc_kernel<<<NBLK, 256, 0, stream>>>(
        X, W_enc1, b_enc1, W_enc2, b_enc2, W_enc3, b_enc3, g_enc, be_enc,
        W_agg, avail, XeBF, acc);

    phi_mfma<false><<<NBLK, 256, 0, stream>>>(
        XeBF, XeBF, Zb, acc, b_agg, W_agg + Ee*Hh, acc + Bb*8, avail,
        W1F, W2F, g_phi, be_phi, W_proj, b_proj, out);

    phi_mfma<false><<<NBLK, 256, 0, stream>>>(
        Zb, XeBF, Zb, acc + Bb*8, b_agg + Hh, W_agg + 2*Ee*Hh, acc + 2*Bb*8, avail,
        W1F + (size_t)7*512, W2F + (size_t)28*512,
        g_phi + EH, be_phi + EH, W_proj, b_proj, out);

    phi_mfma<true><<<NBLK, 256, 0, stream>>>(
        Zb, XeBF, Zb, acc + 2*Bb*8, b_agg + 2*Hh, W_agg, acc, avail,
        W1F + (size_t)14*512, W2F + (size_t)56*512,
        g_phi + 2*EH, be_phi + 2*EH, W_proj, b_proj, out);
}